// Round 19
// baseline (110.581 us; speedup 1.0000x reference)
//
#include <hip/hip_runtime.h>
#include <hip/hip_bf16.h>

#define BB 4
#define NN 8192
#define DD 512
#define EE 8
#define OUTD 512
#define TOPM 1024
#define EPSV 1e-6f
#define ITERS 8

using s16x8 = __attribute__((ext_vector_type(8))) short;
using f32x4 = __attribute__((ext_vector_type(4))) float;
typedef unsigned long long u64;

__device__ __forceinline__ unsigned short f2bf(float f) {
  unsigned u = __float_as_uint(f);
  return (unsigned short)((u + 0x7FFFu + ((u >> 16) & 1u)) >> 16);
}

__device__ __forceinline__ void gll16(const void* g, void* l) {
  __builtin_amdgcn_global_load_lds((const __attribute__((address_space(1))) void*)g,
                                   (__attribute__((address_space(3))) void*)l, 16, 0, 0);
}

// ---- gate logits -> t0 = log(max(x@gw, eps)); x -> bf16; expert transpose ----
__global__ __launch_bounds__(256) void k_gate(const float* __restrict__ x,
                                              const float* __restrict__ gw,
                                              float* __restrict__ t0,
                                              unsigned short* __restrict__ xbf,
                                              int* __restrict__ eo,
                                              int* __restrict__ counts,
                                              const float* __restrict__ W,
                                              unsigned short* __restrict__ WT) {
  const int tid = threadIdx.x;
  if (blockIdx.x >= 2048) {
    __shared__ float tl[32][33];
    const int widx = blockIdx.x - 2048;          // 0..2047
    const int e = widx >> 8, rem = widx & 255;
    const int k0 = (rem >> 4) * 32, n0 = (rem & 15) * 32;
    const int ty = tid >> 5, tx = tid & 31;
    const float* src = W + ((long)e * DD + k0) * OUTD + n0;
#pragma unroll
    for (int j = 0; j < 4; ++j)
      tl[ty + j * 8][tx] = src[(long)(ty + j * 8) * OUTD + tx];
    __syncthreads();
    unsigned short* dst = WT + ((long)e * OUTD + n0) * DD + k0;
#pragma unroll
    for (int j = 0; j < 4; ++j)
      dst[(long)(ty + j * 8) * DD + tx] = f2bf(tl[tx][ty + j * 8]);
    return;
  }
  if (tid < 16) eo[blockIdx.x * 16 + tid] = -1;                   // 2048*16 = 32768
  if (blockIdx.x == 0 && tid >= 64 && tid < 64 + BB * EE) counts[tid - 64] = 0;
  const int lane = tid & 63;
  const int w    = tid >> 6;
  float gwf[64];
  const float* gb = gw + (lane * 8) * EE;
#pragma unroll
  for (int q = 0; q < 16; ++q) {
    float4 t = *(const float4*)(gb + q * 4);
    gwf[q * 4 + 0] = t.x; gwf[q * 4 + 1] = t.y;
    gwf[q * 4 + 2] = t.z; gwf[q * 4 + 3] = t.w;
  }
#pragma unroll
  for (int q = 0; q < 64; ++q) asm volatile("" : "+v"(gwf[q]));   // defeat remat

  const long row0 = (long)blockIdx.x * 16 + w * 4;
  float4 xa[4], xb[4];
#pragma unroll
  for (int i = 0; i < 4; ++i) {
    const float* xr = x + (row0 + i) * DD + lane * 8;
    xa[i] = *(const float4*)(xr);
    xb[i] = *(const float4*)(xr + 4);
  }
  float vout[4];
#pragma unroll
  for (int i = 0; i < 4; ++i) {
    float xv[8] = {xa[i].x, xa[i].y, xa[i].z, xa[i].w,
                   xb[i].x, xb[i].y, xb[i].z, xb[i].w};
    s16x8 xo;
#pragma unroll
    for (int j = 0; j < 8; ++j) xo[j] = (short)f2bf(xv[j]);
    *(s16x8*)(xbf + (row0 + i) * DD + lane * 8) = xo;

    float acc[8] = {0.f,0.f,0.f,0.f,0.f,0.f,0.f,0.f};
#pragma unroll
    for (int q = 0; q < 8; ++q)
#pragma unroll
      for (int e = 0; e < 8; ++e) acc[e] += xv[q] * gwf[q * 8 + e];
    const bool o1 = lane & 1;
    float own, oth, b0, b1, b2, b3, c0, c1, v;
    own = o1 ? acc[1] : acc[0]; oth = o1 ? acc[0] : acc[1];
    b0 = own + __shfl_xor(oth, 1);
    own = o1 ? acc[3] : acc[2]; oth = o1 ? acc[2] : acc[3];
    b1 = own + __shfl_xor(oth, 1);
    own = o1 ? acc[5] : acc[4]; oth = o1 ? acc[4] : acc[5];
    b2 = own + __shfl_xor(oth, 1);
    own = o1 ? acc[7] : acc[6]; oth = o1 ? acc[6] : acc[7];
    b3 = own + __shfl_xor(oth, 1);
    const bool o2 = lane & 2;
    own = o2 ? b1 : b0; oth = o2 ? b0 : b1;
    c0 = own + __shfl_xor(oth, 2);
    own = o2 ? b3 : b2; oth = o2 ? b2 : b3;
    c1 = own + __shfl_xor(oth, 2);
    const bool o4 = lane & 4;
    own = o4 ? c1 : c0; oth = o4 ? c0 : c1;
    v = own + __shfl_xor(oth, 4);
    v += __shfl_xor(v, 8);
    v += __shfl_xor(v, 16);
    v += __shfl_xor(v, 32);
    vout[i] = v;              // e = lane&7, all lanes
  }
  const int gsel = lane >> 3;
  float vsel = vout[0];
  vsel = (gsel == 1) ? vout[1] : vsel;
  vsel = (gsel == 2) ? vout[2] : vsel;
  vsel = (gsel == 3) ? vout[3] : vsel;
  if (lane < 32) t0[row0 * EE + lane] = logf(fmaxf(vsel, EPSV));
}

// ---- fused Sinkhorn + exact top-1024 radix select (spilled-remat accepted:
// ---- r15-r18 showed the allocator refuses >~32 live f32/thread) ----
__global__ __launch_bounds__(1024) void k_topk(const float* __restrict__ t0,
                                               float* __restrict__ R,
                                               float* __restrict__ C,
                                               int* __restrict__ expert_of) {
  __shared__ unsigned key[NN];            // 32 KiB (holds tvm bits during Sinkhorn)
  __shared__ int hist[256];
  __shared__ int bcast[2];
  __shared__ int wsum[16];
  __shared__ float ws[16][8], Csh[8], Ssh[8];
  const int b = blockIdx.x >> 3, e = blockIdx.x & 7;
  const int tid = threadIdx.x;
  const int wv = tid >> 6, ln = tid & 63;
  const float* tb = t0 + (long)b * NN * EE;

  float E[8][8], u[8], dl[8];
#pragma unroll
  for (int j = 0; j < 8; ++j) {
    const float* p = tb + (long)(j * 1024 + tid) * EE;
    float4 a = *(const float4*)p, b4 = *(const float4*)(p + 4);
    E[j][0] = expf(a.x);  E[j][1] = expf(a.y);
    E[j][2] = expf(a.z);  E[j][3] = expf(a.w);
    E[j][4] = expf(b4.x); E[j][5] = expf(b4.y);
    E[j][6] = expf(b4.z); E[j][7] = expf(b4.w);
    key[j * 1024 + tid] = __float_as_uint(p[e]);   // park own-expert t0 in LDS
    u[j] = 1.f;
  }
  for (int it = 0; it < ITERS; ++it) {
    float P[8] = {0.f,0.f,0.f,0.f,0.f,0.f,0.f,0.f};
#pragma unroll
    for (int j = 0; j < 8; ++j)
#pragma unroll
      for (int e2 = 0; e2 < 8; ++e2) P[e2] += E[j][e2] * u[j];
#pragma unroll
    for (int d = 1; d <= 4; d <<= 1) {
#pragma unroll
      for (int e2 = 0; e2 < 8; ++e2) {
        float tmp = __shfl_xor(P[e2], d);
        P[e2] += ((ln & d) == (e2 & d)) ? tmp : 0.f;
      }
    }
    float pv = P[0];
#pragma unroll
    for (int e2 = 1; e2 < 8; ++e2) pv = ((ln & 7) == e2) ? P[e2] : pv;
#pragma unroll
    for (int d = 8; d < 64; d <<= 1) pv += __shfl_xor(pv, d);
    if (ln < 8) ws[wv][ln] = pv;
    __syncthreads();
    if (tid < 64) {
      const int q = ln >> 3, e2 = ln & 7;
      float s = ws[q][e2] + ws[q + 8][e2];
#pragma unroll
      for (int d = 8; d < 64; d <<= 1) s += __shfl_xor(s, d);
      if (ln < 8) { Csh[ln] = 1.f / s; Ssh[ln] = s; }
    }
    __syncthreads();
    float vv[8];
#pragma unroll
    for (int e2 = 0; e2 < 8; ++e2) vv[e2] = Csh[e2];
#pragma unroll
    for (int j = 0; j < 8; ++j) {
      float d0 = E[j][0] * vv[0];
#pragma unroll
      for (int e2 = 1; e2 < 8; ++e2) d0 += E[j][e2] * vv[e2];
      dl[j] = d0;
      u[j] = 1.f / d0;
    }
    __syncthreads();   // protect ws/Csh WAR before next iteration's writes
  }
  if (e == 0) {        // one block per batch persists R/C for k_post
#pragma unroll
    for (int j = 0; j < 8; ++j) R[(long)b * NN + j * 1024 + tid] = logf(dl[j]);
    if (tid < 8) C[b * EE + tid] = logf(Ssh[tid]);
  }

  if (tid < 256) hist[tid] = 0;
  __syncthreads();
#pragma unroll
  for (int j = 0; j < 8; ++j) {
    const int n = j * 1024 + tid;
    float f = __uint_as_float(key[n]) - logf(dl[j]);
    unsigned uk = __float_as_uint(f);
    uk = (uk & 0x80000000u) ? ~uk : (uk | 0x80000000u);   // sortable
    key[n] = uk;
    atomicAdd(&hist[uk >> 24], 1);
  }
  __syncthreads();
  unsigned prefix = 0, mask = 0;
  int k = TOPM;
  for (int shift = 24; shift >= 0; shift -= 8) {
    if (tid < 64) {
      const int4 h4 = *(const int4*)&hist[ln * 4];
      const int r3 = h4.w, r2 = h4.z + r3, r1 = h4.y + r2, r0 = h4.x + r1;
      int suf = r0;
#pragma unroll
      for (int d = 1; d < 64; d <<= 1) {
        int o = __shfl_down(suf, d);
        if (ln + d < 64) suf += o;
      }
      const int above = suf - r0;
      const int cum0 = above + r0, cum1 = above + r1;
      const int cum2 = above + r2, cum3 = above + r3;
      if (cum0 >= k && cum1 < k) { bcast[0] = k - cum1; bcast[1] = ln * 4 + 0; }
      if (cum1 >= k && cum2 < k) { bcast[0] = k - cum2; bcast[1] = ln * 4 + 1; }
      if (cum2 >= k && cum3 < k) { bcast[0] = k - cum3; bcast[1] = ln * 4 + 2; }
      if (cum3 >= k && above < k) { bcast[0] = k - above; bcast[1] = ln * 4 + 3; }
    }
    __syncthreads();
    k = bcast[0];
    prefix |= ((unsigned)bcast[1]) << shift;
    mask |= (255u << shift);
    if (shift == 0) break;
    if (tid < 256) hist[tid] = 0;
    __syncthreads();
    const int nsh = shift - 8;
    for (int n = tid; n < NN; n += 1024) {
      unsigned uk = key[n];
      if ((uk & mask) == prefix) atomicAdd(&hist[(uk >> nsh) & 255], 1);
    }
    __syncthreads();
  }
  const unsigned theta = prefix;
  const int need = k;
  const int base = tid * 8;
  int c = 0;
#pragma unroll
  for (int j = 0; j < 8; ++j) if (key[base + j] == theta) ++c;
  int inc = c;
#pragma unroll
  for (int d = 1; d < 64; d <<= 1) {
    int o = __shfl_up(inc, d);
    if (ln >= d) inc += o;
  }
  if (ln == 63) wsum[wv] = inc;
  __syncthreads();
  if (tid == 0) {
    int runv = 0;
    for (int i = 0; i < 16; ++i) { int t2 = wsum[i]; wsum[i] = runv; runv += t2; }
  }
  __syncthreads();
  int run = wsum[wv] + inc - c;
  int* eo = expert_of + b * NN;
  for (int j = 0; j < 8; ++j) {
    int n = base + j;
    unsigned uk = key[n];
    bool sel = false;
    if (uk > theta) sel = true;
    else if (uk == theta) { if (run < need) sel = true; ++run; }
    if (sel) atomicMax(&eo[n], e);     // np scatter: largest expert index wins
  }
}

// ---- merged: compact lists + gates (blocks 0..127) ; zero unselected rows ----
__global__ __launch_bounds__(256) void k_post(const int* __restrict__ expert_of,
                                              const float* __restrict__ t0,
                                              const float* __restrict__ R,
                                              const float* __restrict__ C,
                                              int* __restrict__ counts,
                                              int* __restrict__ lists,
                                              float* __restrict__ gvals,
                                              float* __restrict__ out) {
  const int tid = threadIdx.x;
  if (blockIdx.x >= 128) {
    const int row = (blockIdx.x - 128) * 4 + (tid >> 6);
    if (expert_of[row] >= 0) return;
    const int ln = tid & 63;
    float4 z = make_float4(0.f, 0.f, 0.f, 0.f);
    float4* p = (float4*)(out + (long)row * OUTD) + ln;
    p[0] = z; p[64] = z;
    return;
  }
  __shared__ int hist8[8], base8[8];
  if (tid < 8) hist8[tid] = 0;
  __syncthreads();
  const long i = (long)blockIdx.x * 256 + tid;
  const int b = (int)(i >> 13);
  const int e = expert_of[i];
  int lpos = -1;
  if (e >= 0) lpos = atomicAdd(&hist8[e], 1);
  __syncthreads();
  if (tid < 8 && hist8[tid] > 0)
    base8[tid] = atomicAdd(&counts[b * EE + tid], hist8[tid]);
  __syncthreads();
  if (e >= 0) {
    const int n = (int)(i & (NN - 1));
    const int be = b * EE + e;
    const int slot = be * TOPM + base8[e] + lpos;
    lists[slot] = n;
    gvals[slot] = expf(t0[i * EE + e] - C[be] - R[i]);
  }
}

// ---- gathered bf16 MFMA GEMM v4: BK=32, TRIPLE-buffered LDS, prefetch depth 2,
// ---- raw s_barrier + counted vmcnt(4) (never 0 in-loop): loads stay in flight
// ---- across barriers. Swizzle: 4-slot, c_r=(row^(row>>2))&3 involution on both
// ---- the pre-swizzled global source and the ds_read side.
__global__ __launch_bounds__(256) void k_gemm(const unsigned short* __restrict__ xbf,
                                              const unsigned short* __restrict__ WT,
                                              const int* __restrict__ counts,
                                              const int* __restrict__ lists,
                                              const float* __restrict__ gvals,
                                              float* __restrict__ out) {
  const int id = blockIdx.x;                 // 1024 = xq*256 + be*8 + yq
  const int xq = id >> 8;                    // 0..3  col tile (A-sharing -> same XCD)
  const int be = (id >> 3) & 31;             // b*8+e
  const int yq = id & 7;                     // 0..7  row tile
  const int b = be >> 3, e = be & 7;
  const int cnt = counts[be];
  const int r0 = yq * 128;
  if (r0 >= cnt) return;
  const int c0 = xq * 128;

  __shared__ unsigned short As[3][128 * 32]; // 3 x 8 KiB
  __shared__ unsigned short Bs[3][128 * 32]; // 3 x 8 KiB
  __shared__ int   rowTok[128];
  __shared__ float rowG[128];

  const int tid = threadIdx.x;
  if (tid < 128) {
    int r = r0 + tid;
    rowTok[tid] = (r < cnt) ? lists[be * TOPM + r] : -1;
    rowG[tid]   = (r < cnt) ? gvals[be * TOPM + r] : 0.f;
  }
  __syncthreads();

  const int w = tid >> 6, l = tid & 63;
  // staging: wave w, call c covers rows w*32+c*16 .. +16; lane -> row (l>>2), slot l&3
  const unsigned short* xb_b = xbf + (long)b * NN * DD;
  const unsigned short* wt_e = WT + (long)e * OUTD * DD;
  const unsigned short* gA[2];
  const unsigned short* gB[2];
#pragma unroll
  for (int c = 0; c < 2; ++c) {
    int r = w * 32 + c * 16 + (l >> 2);
    int cr = (r ^ (r >> 2)) & 3;
    int tk = rowTok[r]; if (tk < 0) tk = 0;
    gA[c] = xb_b + (long)tk * DD + (((l & 3) ^ cr) * 8);
    gB[c] = wt_e + (long)(c0 + r) * DD + (((l & 3) ^ cr) * 8);
  }

  const int wr = w >> 1, wc = w & 1;
  const int fr = l & 15, fq = l >> 4;
  int aoff[4], boff[4];
#pragma unroll
  for (int m = 0; m < 4; ++m) {
    int row = wr * 64 + m * 16 + fr;
    int cr = (row ^ (row >> 2)) & 3;
    aoff[m] = row * 32 + ((fq ^ cr) * 8);
    int col = wc * 64 + m * 16 + fr;
    int cc = (col ^ (col >> 2)) & 3;
    boff[m] = col * 32 + ((fq ^ cc) * 8);
  }

  f32x4 acc[4][4] = {};

#define STAGE(kb, p) {                                                       \
    int ko = (kb) * 32;                                                      \
    gll16(gA[0] + ko, &As[p][(w * 32 +  0) * 32]);                           \
    gll16(gA[1] + ko, &As[p][(w * 32 + 16) * 32]);                           \
    gll16(gB[0] + ko, &Bs[p][(w * 32 +  0) * 32]);                           \
    gll16(gB[1] + ko, &Bs[p][(w * 32 + 16) * 32]);                           \
  }

  STAGE(0, 0);
  STAGE(1, 1);
  for (int kb = 0; kb < 16; ++kb) {
    const int p = kb - (kb / 3) * 3;           // kb % 3
    // counted wait: 2 stages (8 loads/wave? 4/wave each) outstanding; need kb's 4 done
    if (kb < 15) asm volatile("s_waitcnt vmcnt(4)" ::: "memory");
    else         asm volatile("s_waitcnt vmcnt(0)" ::: "memory");
    __builtin_amdgcn_s_barrier();
    s16x8 af[4], bf_[4];
#pragma unroll
    for (int m = 0; m < 4; ++m) af[m] = *(const s16x8*)(&As[p][0] + aoff[m]);
#pragma unroll
    for (int n = 0; n < 4; ++n) bf_[n] = *(const s16x8*)(&Bs[p][0] + boff[n]);
    if (kb < 14) {
      const int p2 = (kb + 2) - ((kb + 2) / 3) * 3;
      STAGE(kb + 2, p2);
    }
#pragma unroll
    for (int m = 0; m < 4; ++m)
#pragma unroll
      for (int n = 0; n < 4; ++n)
        acc[m][n] = __builtin_amdgcn_mfma_f32_16x16x32_bf16(af[m], bf_[n], acc[m][n], 0, 0, 0);
  }
#undef STAGE

  // epilogue: C/D layout col=lane&15, row=(lane>>4)*4+reg
#pragma unroll
  for (int m = 0; m < 4; ++m) {
    int rbase2 = wr * 64 + m * 16 + fq * 4;
    int tok[4]; float g[4];
#pragma unroll
    for (int j = 0; j < 4; ++j) { tok[j] = rowTok[rbase2 + j]; g[j] = rowG[rbase2 + j]; }
#pragma unroll
    for (int n = 0; n < 4; ++n) {
      int col = c0 + wc * 64 + n * 16 + fr;
#pragma unroll
      for (int j = 0; j < 4; ++j) {
        if (tok[j] >= 0)
          out[((long)b * NN + tok[j]) * OUTD + col] = acc[m][n][j] * g[j];
      }
    }
  }
}

extern "C" void kernel_launch(void* const* d_in, const int* in_sizes, int n_in,
                              void* d_out, int out_size, void* d_ws, size_t ws_size,
                              hipStream_t stream) {
  const float* x  = (const float*)d_in[0];
  const float* gw = (const float*)d_in[1];
  const float* ex = (const float*)d_in[2];
  float* out = (float*)d_out;

  char* wsb = (char*)d_ws;
  float*          t0     = (float*)(wsb);                          // 1 MiB
  unsigned short* xbf    = (unsigned short*)(wsb + (1l << 20));    // 32 MiB
  unsigned short* WT     = (unsigned short*)(wsb + (33l << 20));   // 4 MiB
  const long base = 37l << 20;
  float*          R      = (float*)(wsb + base);                           // 128 KiB
  int*            eo     = (int*)  (wsb + base + (128l << 10));            // 128 KiB
  int*            lists  = (int*)  (wsb + base + (256l << 10));            // 128 KiB
  float*          gvals  = (float*)(wsb + base + (384l << 10));            // 128 KiB
  float*          C      = (float*)(wsb + base + (512l << 10));            // 32 B
  int*            counts = (int*)  (wsb + base + (512l << 10) + 1024);     // 128 B

  k_gate<<<2048 + 2048, 256, 0, stream>>>(x, gw, t0, xbf, eo, counts, ex, WT);
  k_topk<<<BB * EE, 1024, 0, stream>>>(t0, R, C, eo);
  k_post<<<128 + (BB * NN) / 4, 256, 0, stream>>>(eo, t0, R, C, counts, lists, gvals, out);
  k_gemm<<<1024, 256, 0, stream>>>(xbf, WT, counts, lists, gvals, out);
}

// Round 21
// 104.878 us; speedup vs baseline: 1.0544x; 1.0544x over previous
//
#include <hip/hip_runtime.h>
#include <hip/hip_bf16.h>

#define BB 4
#define NN 8192
#define DD 512
#define EE 8
#define OUTD 512
#define TOPM 1024
#define EPSV 1e-6f
#define ITERS 8

using s16x8 = __attribute__((ext_vector_type(8))) short;
using f32x4 = __attribute__((ext_vector_type(4))) float;
typedef unsigned long long u64;

__device__ __forceinline__ unsigned short f2bf(float f) {
  unsigned u = __float_as_uint(f);
  return (unsigned short)((u + 0x7FFFu + ((u >> 16) & 1u)) >> 16);
}

__device__ __forceinline__ void gll16(const void* g, void* l) {
  __builtin_amdgcn_global_load_lds((const __attribute__((address_space(1))) void*)g,
                                   (__attribute__((address_space(3))) void*)l, 16, 0, 0);
}

// ---- gate logits -> t0 = log(max(x@gw, eps)); x -> bf16; expert transpose ----
// 4 rows/wave; gw held in 64 VGPRs (asm keep-alive), x loads batched up front.
__global__ __launch_bounds__(256) void k_gate(const float* __restrict__ x,
                                              const float* __restrict__ gw,
                                              float* __restrict__ t0,
                                              unsigned short* __restrict__ xbf,
                                              int* __restrict__ eo,
                                              int* __restrict__ counts,
                                              const float* __restrict__ W,
                                              unsigned short* __restrict__ WT) {
  const int tid = threadIdx.x;
  if (blockIdx.x >= 2048) {
    // ---- expert transpose: f32 [e][k][n] -> bf16 [e][n][k], 32x32 tiles ----
    __shared__ float tl[32][33];
    const int widx = blockIdx.x - 2048;          // 0..2047
    const int e = widx >> 8, rem = widx & 255;
    const int k0 = (rem >> 4) * 32, n0 = (rem & 15) * 32;
    const int ty = tid >> 5, tx = tid & 31;
    const float* src = W + ((long)e * DD + k0) * OUTD + n0;
#pragma unroll
    for (int j = 0; j < 4; ++j)
      tl[ty + j * 8][tx] = src[(long)(ty + j * 8) * OUTD + tx];
    __syncthreads();
    unsigned short* dst = WT + ((long)e * OUTD + n0) * DD + k0;
#pragma unroll
    for (int j = 0; j < 4; ++j)
      dst[(long)(ty + j * 8) * DD + tx] = f2bf(tl[tx][ty + j * 8]);
    return;
  }
  if (tid < 16) eo[blockIdx.x * 16 + tid] = -1;                   // 2048*16 = 32768
  if (blockIdx.x == 0 && tid >= 64 && tid < 64 + BB * EE) counts[tid - 64] = 0;
  const int lane = tid & 63;
  const int w    = tid >> 6;
  // gw[k][e], k = lane*8 .. lane*8+7 -> 64 floats, forced register-resident
  float gwf[64];
  const float* gb = gw + (lane * 8) * EE;
#pragma unroll
  for (int q = 0; q < 16; ++q) {
    float4 t = *(const float4*)(gb + q * 4);
    gwf[q * 4 + 0] = t.x; gwf[q * 4 + 1] = t.y;
    gwf[q * 4 + 2] = t.z; gwf[q * 4 + 3] = t.w;
  }
#pragma unroll
  for (int q = 0; q < 64; ++q) asm volatile("" : "+v"(gwf[q]));   // defeat remat

  const long row0 = (long)blockIdx.x * 16 + w * 4;
  float4 xa[4], xb[4];
#pragma unroll
  for (int i = 0; i < 4; ++i) {
    const float* xr = x + (row0 + i) * DD + lane * 8;
    xa[i] = *(const float4*)(xr);
    xb[i] = *(const float4*)(xr + 4);
  }
  float vout[4];
#pragma unroll
  for (int i = 0; i < 4; ++i) {
    float xv[8] = {xa[i].x, xa[i].y, xa[i].z, xa[i].w,
                   xb[i].x, xb[i].y, xb[i].z, xb[i].w};
    s16x8 xo;
#pragma unroll
    for (int j = 0; j < 8; ++j) xo[j] = (short)f2bf(xv[j]);
    *(s16x8*)(xbf + (row0 + i) * DD + lane * 8) = xo;

    float acc[8] = {0.f,0.f,0.f,0.f,0.f,0.f,0.f,0.f};
#pragma unroll
    for (int q = 0; q < 8; ++q)
#pragma unroll
      for (int e = 0; e < 8; ++e) acc[e] += xv[q] * gwf[q * 8 + e];
    // select+shuffle halving fold: 8 arrays -> e=lane&7 in 7 shuffles, +3 wide
    const bool o1 = lane & 1;
    float own, oth, b0, b1, b2, b3, c0, c1, v;
    own = o1 ? acc[1] : acc[0]; oth = o1 ? acc[0] : acc[1];
    b0 = own + __shfl_xor(oth, 1);
    own = o1 ? acc[3] : acc[2]; oth = o1 ? acc[2] : acc[3];
    b1 = own + __shfl_xor(oth, 1);
    own = o1 ? acc[5] : acc[4]; oth = o1 ? acc[4] : acc[5];
    b2 = own + __shfl_xor(oth, 1);
    own = o1 ? acc[7] : acc[6]; oth = o1 ? acc[6] : acc[7];
    b3 = own + __shfl_xor(oth, 1);
    const bool o2 = lane & 2;
    own = o2 ? b1 : b0; oth = o2 ? b0 : b1;
    c0 = own + __shfl_xor(oth, 2);
    own = o2 ? b3 : b2; oth = o2 ? b2 : b3;
    c1 = own + __shfl_xor(oth, 2);
    const bool o4 = lane & 4;
    own = o4 ? c1 : c0; oth = o4 ? c0 : c1;
    v = own + __shfl_xor(oth, 4);
    v += __shfl_xor(v, 8);
    v += __shfl_xor(v, 16);
    v += __shfl_xor(v, 32);
    vout[i] = v;              // e = lane&7, all lanes
  }
  // coalesced t0 store: lanes 0..31 cover 4 rows x 8 experts
  const int gsel = lane >> 3;
  float vsel = vout[0];
  vsel = (gsel == 1) ? vout[1] : vsel;
  vsel = (gsel == 2) ? vout[2] : vsel;
  vsel = (gsel == 3) ? vout[3] : vsel;
  if (lane < 32) t0[row0 * EE + lane] = logf(fmaxf(vsel, EPSV));
}

// ---- fused: linear-domain Sinkhorn (redundant per e-block, bit-identical) +
// ---- exact top-1024 radix select. (r15-r18: allocator remats E regardless of
// ---- attributes/LDS pressure; accepted. tvm parked in key[] LDS.)
__global__ __attribute__((amdgpu_waves_per_eu(4, 4)))
__launch_bounds__(1024) void k_topk(const float* __restrict__ t0,
                                    float* __restrict__ R,
                                    float* __restrict__ C,
                                    int* __restrict__ expert_of) {
  __shared__ unsigned key[NN];            // 32 KiB (holds tvm bits during Sinkhorn)
  __shared__ int hist[256];
  __shared__ int bcast[2];
  __shared__ int wsum[16];
  __shared__ float ws[16][8], Csh[8], Ssh[8];
  const int b = blockIdx.x >> 3, e = blockIdx.x & 7;
  const int tid = threadIdx.x;
  const int wv = tid >> 6, ln = tid & 63;
  const float* tb = t0 + (long)b * NN * EE;

  // ---- Sinkhorn: thread owns rows {j*1024+tid}; E = exp(t0); u = 1/D; v = 1/S ----
  float E[8][8], u[8], dl[8];
#pragma unroll
  for (int j = 0; j < 8; ++j) {
    const float* p = tb + (long)(j * 1024 + tid) * EE;
    float4 a = *(const float4*)p, b4 = *(const float4*)(p + 4);
    E[j][0] = expf(a.x);  E[j][1] = expf(a.y);
    E[j][2] = expf(a.z);  E[j][3] = expf(a.w);
    E[j][4] = expf(b4.x); E[j][5] = expf(b4.y);
    E[j][6] = expf(b4.z); E[j][7] = expf(b4.w);
    key[j * 1024 + tid] = __float_as_uint(p[e]);   // park own-expert t0 in LDS
    u[j] = 1.f;
  }
#pragma unroll
  for (int j = 0; j < 8; ++j)
#pragma unroll
    for (int e2 = 0; e2 < 8; ++e2)
      asm volatile("" : "+v"(E[j][e2]));           // keep-alive (best effort)
  for (int it = 0; it < ITERS; ++it) {
    float P[8] = {0.f,0.f,0.f,0.f,0.f,0.f,0.f,0.f};
#pragma unroll
    for (int j = 0; j < 8; ++j)
#pragma unroll
      for (int e2 = 0; e2 < 8; ++e2) P[e2] += E[j][e2] * u[j];
#pragma unroll
    for (int d = 1; d <= 4; d <<= 1) {
#pragma unroll
      for (int e2 = 0; e2 < 8; ++e2) {
        float tmp = __shfl_xor(P[e2], d);
        P[e2] += ((ln & d) == (e2 & d)) ? tmp : 0.f;
      }
    }
    float pv = P[0];
#pragma unroll
    for (int e2 = 1; e2 < 8; ++e2) pv = ((ln & 7) == e2) ? P[e2] : pv;
#pragma unroll
    for (int d = 8; d < 64; d <<= 1) pv += __shfl_xor(pv, d);
    if (ln < 8) ws[wv][ln] = pv;
    __syncthreads();
    if (tid < 64) {
      const int q = ln >> 3, e2 = ln & 7;
      float s = ws[q][e2] + ws[q + 8][e2];
#pragma unroll
      for (int d = 8; d < 64; d <<= 1) s += __shfl_xor(s, d);
      if (ln < 8) { Csh[ln] = 1.f / s; Ssh[ln] = s; }
    }
    __syncthreads();
    float vv[8];
#pragma unroll
    for (int e2 = 0; e2 < 8; ++e2) vv[e2] = Csh[e2];
#pragma unroll
    for (int j = 0; j < 8; ++j) {
      float d0 = E[j][0] * vv[0];
#pragma unroll
      for (int e2 = 1; e2 < 8; ++e2) d0 += E[j][e2] * vv[e2];
      dl[j] = d0;
      u[j] = 1.f / d0;
    }
    __syncthreads();   // protect ws/Csh WAR before next iteration's writes
  }
  if (e == 0) {        // one block per batch persists R/C for k_post
#pragma unroll
    for (int j = 0; j < 8; ++j) R[(long)b * NN + j * 1024 + tid] = logf(dl[j]);
    if (tid < 8) C[b * EE + tid] = logf(Ssh[tid]);
  }

  // ---- keys + pass-1 histogram (tvm from LDS, R register-local: logf(dl)) ----
  if (tid < 256) hist[tid] = 0;
  __syncthreads();
#pragma unroll
  for (int j = 0; j < 8; ++j) {
    const int n = j * 1024 + tid;
    float f = __uint_as_float(key[n]) - logf(dl[j]);
    unsigned uk = __float_as_uint(f);
    uk = (uk & 0x80000000u) ? ~uk : (uk | 0x80000000u);   // sortable
    key[n] = uk;
    atomicAdd(&hist[uk >> 24], 1);
  }
  __syncthreads();
  unsigned prefix = 0, mask = 0;
  int k = TOPM;
  for (int shift = 24; shift >= 0; shift -= 8) {
    // wave 0: suffix-scan of 256 bins, find boundary (no block barriers inside)
    if (tid < 64) {
      const int4 h4 = *(const int4*)&hist[ln * 4];
      const int r3 = h4.w, r2 = h4.z + r3, r1 = h4.y + r2, r0 = h4.x + r1;
      int suf = r0;
#pragma unroll
      for (int d = 1; d < 64; d <<= 1) {
        int o = __shfl_down(suf, d);
        if (ln + d < 64) suf += o;
      }
      const int above = suf - r0;          // sum over lanes > ln
      const int cum0 = above + r0, cum1 = above + r1;
      const int cum2 = above + r2, cum3 = above + r3;
      if (cum0 >= k && cum1 < k) { bcast[0] = k - cum1; bcast[1] = ln * 4 + 0; }
      if (cum1 >= k && cum2 < k) { bcast[0] = k - cum2; bcast[1] = ln * 4 + 1; }
      if (cum2 >= k && cum3 < k) { bcast[0] = k - cum3; bcast[1] = ln * 4 + 2; }
      if (cum3 >= k && above < k) { bcast[0] = k - above; bcast[1] = ln * 4 + 3; }
    }
    __syncthreads();
    k = bcast[0];
    prefix |= ((unsigned)bcast[1]) << shift;
    mask |= (255u << shift);
    if (shift == 0) break;
    if (tid < 256) hist[tid] = 0;
    __syncthreads();
    const int nsh = shift - 8;
    for (int n = tid; n < NN; n += 1024) {
      unsigned uk = key[n];
      if ((uk & mask) == prefix) atomicAdd(&hist[(uk >> nsh) & 255], 1);
    }
    __syncthreads();
  }
  const unsigned theta = prefix;
  const int need = k;                  // ties (==theta) to take, lowest index first
  const int base = tid * 8;            // contiguous chunks -> deterministic index order
  int c = 0;
#pragma unroll
  for (int j = 0; j < 8; ++j) if (key[base + j] == theta) ++c;
  int inc = c;
#pragma unroll
  for (int d = 1; d < 64; d <<= 1) {
    int o = __shfl_up(inc, d);
    if (ln >= d) inc += o;
  }
  if (ln == 63) wsum[wv] = inc;
  __syncthreads();
  if (tid == 0) {
    int runv = 0;
    for (int i = 0; i < 16; ++i) { int t2 = wsum[i]; wsum[i] = runv; runv += t2; }
  }
  __syncthreads();
  int run = wsum[wv] + inc - c;        // exclusive prefix of this thread's ties
  int* eo = expert_of + b * NN;
  for (int j = 0; j < 8; ++j) {
    int n = base + j;
    unsigned uk = key[n];
    bool sel = false;
    if (uk > theta) sel = true;
    else if (uk == theta) { if (run < need) sel = true; ++run; }
    if (sel) atomicMax(&eo[n], e);     // np scatter: largest expert index wins
  }
}

// ---- compact per-(b,e) token lists + gate values (list-build only; 128 blocks) ----
__global__ __launch_bounds__(256) void k_post(const int* __restrict__ expert_of,
                                              const float* __restrict__ t0,
                                              const float* __restrict__ R,
                                              const float* __restrict__ C,
                                              int* __restrict__ counts,
                                              int* __restrict__ lists,
                                              float* __restrict__ gvals) {
  __shared__ int hist8[8], base8[8];
  const int tid = threadIdx.x;
  if (tid < 8) hist8[tid] = 0;
  __syncthreads();
  const long i = (long)blockIdx.x * 256 + tid;     // block within one batch
  const int b = (int)(i >> 13);
  const int e = expert_of[i];
  int lpos = -1;
  if (e >= 0) lpos = atomicAdd(&hist8[e], 1);      // LDS atomic: ns-scale
  __syncthreads();
  if (tid < 8 && hist8[tid] > 0)
    base8[tid] = atomicAdd(&counts[b * EE + tid], hist8[tid]);  // 1 RMW per (block,e)
  __syncthreads();
  if (e >= 0) {
    const int n = (int)(i & (NN - 1));
    const int be = b * EE + e;
    const int slot = be * TOPM + base8[e] + lpos;
    lists[slot] = n;
    gvals[slot] = expf(t0[i * EE + e] - C[be] - R[i]);
  }
}

// ---- gathered bf16 MFMA GEMM v2 (blocks 0..1023) + zero unselected rows (1024+) ----
__global__ __launch_bounds__(256) void k_gemm(const unsigned short* __restrict__ xbf,
                                              const unsigned short* __restrict__ WT,
                                              const int* __restrict__ counts,
                                              const int* __restrict__ lists,
                                              const float* __restrict__ gvals,
                                              const int* __restrict__ eo,
                                              float* __restrict__ out) {
  const int tid = threadIdx.x;
  if (blockIdx.x >= 1024) {
    // zero output rows of unselected tokens (backfills CUs behind gemm tiles)
    const int row = (blockIdx.x - 1024) * 4 + (tid >> 6);
    if (eo[row] >= 0) return;
    const int ln = tid & 63;
    float4 z = make_float4(0.f, 0.f, 0.f, 0.f);
    float4* p = (float4*)(out + (long)row * OUTD) + ln;
    p[0] = z; p[64] = z;
    return;
  }
  const int id = blockIdx.x;                 // 1024 = xq*256 + be*8 + yq
  const int xq = id >> 8;                    // 0..3  col tile (A-sharing -> same XCD)
  const int be = (id >> 3) & 31;             // b*8+e
  const int yq = id & 7;                     // 0..7  row tile
  const int b = be >> 3, e = be & 7;
  const int cnt = counts[be];
  const int r0 = yq * 128;
  if (r0 >= cnt) return;
  const int c0 = xq * 128;

  __shared__ unsigned short As[128 * 64];    // 16 KiB
  __shared__ unsigned short Bs[128 * 64];    // 16 KiB
  __shared__ int   rowTok[128];
  __shared__ float rowG[128];

  if (tid < 128) {
    int r = r0 + tid;
    rowTok[tid] = (r < cnt) ? lists[be * TOPM + r] : -1;
    rowG[tid]   = (r < cnt) ? gvals[be * TOPM + r] : 0.f;
  }
  __syncthreads();

  const int w = tid >> 6, l = tid & 63;
  const int rbase = w * 32 + (l >> 3);
  const int sL = l & 7;
  const unsigned short* xb_b = xbf + (long)b * NN * DD;
  const unsigned short* wt_e = WT + (long)e * OUTD * DD;
  int tokc[4]; int sGa[4];
#pragma unroll
  for (int c = 0; c < 4; ++c) {
    int r = rbase + c * 8;
    int tk = rowTok[r]; if (tk < 0) tk = 0;
    tokc[c] = tk;
    sGa[c] = (sL ^ (r & 7)) * 8;             // pre-swizzled global k-slot (elems)
  }

  const int wr = w >> 1, wc = w & 1;
  const int fr = l & 15, fq = l >> 4;
  int aoff[4][2], boff[4][2];
#pragma unroll
  for (int m = 0; m < 4; ++m) {
#pragma unroll
    for (int kk = 0; kk < 2; ++kk) {
      int row = wr * 64 + m * 16 + fr;
      aoff[m][kk] = row * 64 + (((fq + 4 * kk) ^ (row & 7)) * 8);
      int col = wc * 64 + m * 16 + fr;
      boff[m][kk] = col * 64 + (((fq + 4 * kk) ^ (col & 7)) * 8);
    }
  }

  f32x4 acc[4][4] = {};

#define STAGE(kb) {                                                          \
    int ko = (kb) * 64;                                                      \
    _Pragma("unroll")                                                        \
    for (int c = 0; c < 4; ++c) {                                            \
      int r = rbase + c * 8;                                                 \
      gll16(xb_b + (long)tokc[c] * DD + ko + sGa[c],                         \
            As + (w * 32 + c * 8) * 64);                                     \
      gll16(wt_e + (long)(c0 + r) * DD + ko + sGa[c],                        \
            Bs + (w * 32 + c * 8) * 64);                                     \
    }                                                                        \
  }

  STAGE(0);
  for (int kb = 0; kb < 8; ++kb) {
    __syncthreads();
    s16x8 af[4][2], bf_[4][2];
#pragma unroll
    for (int m = 0; m < 4; ++m) {
      af[m][0] = *(const s16x8*)(As + aoff[m][0]);
      af[m][1] = *(const s16x8*)(As + aoff[m][1]);
      bf_[m][0] = *(const s16x8*)(Bs + boff[m][0]);
      bf_[m][1] = *(const s16x8*)(Bs + boff[m][1]);
    }
    __syncthreads();
    if (kb < 7) STAGE(kb + 1);
#pragma unroll
    for (int kk = 0; kk < 2; ++kk)
#pragma unroll
      for (int m = 0; m < 4; ++m)
#pragma unroll
        for (int n = 0; n < 4; ++n)
          acc[m][n] = __builtin_amdgcn_mfma_f32_16x16x32_bf16(af[m][kk], bf_[n][kk], acc[m][n], 0, 0, 0);
  }
#undef STAGE

  // epilogue: C/D layout col=lane&15, row=(lane>>4)*4+reg
#pragma unroll
  for (int m = 0; m < 4; ++m) {
    int rbase2 = wr * 64 + m * 16 + fq * 4;
    int tok[4]; float g[4];
#pragma unroll
    for (int j = 0; j < 4; ++j) { tok[j] = rowTok[rbase2 + j]; g[j] = rowG[rbase2 + j]; }
#pragma unroll
    for (int n = 0; n < 4; ++n) {
      int col = c0 + wc * 64 + n * 16 + fr;
#pragma unroll
      for (int j = 0; j < 4; ++j) {
        if (tok[j] >= 0)
          out[((long)b * NN + tok[j]) * OUTD + col] = acc[m][n][j] * g[j];
      }
    }
  }
}

extern "C" void kernel_launch(void* const* d_in, const int* in_sizes, int n_in,
                              void* d_out, int out_size, void* d_ws, size_t ws_size,
                              hipStream_t stream) {
  const float* x  = (const float*)d_in[0];
  const float* gw = (const float*)d_in[1];
  const float* ex = (const float*)d_in[2];
  float* out = (float*)d_out;

  char* wsb = (char*)d_ws;
  float*          t0     = (float*)(wsb);                          // 1 MiB
  unsigned short* xbf    = (unsigned short*)(wsb + (1l << 20));    // 32 MiB
  unsigned short* WT     = (unsigned short*)(wsb + (33l << 20));   // 4 MiB
  const long base = 37l << 20;
  float*          R      = (float*)(wsb + base);                           // 128 KiB
  int*            eo     = (int*)  (wsb + base + (128l << 10));            // 128 KiB
  int*            lists  = (int*)  (wsb + base + (256l << 10));            // 128 KiB
  float*          gvals  = (float*)(wsb + base + (384l << 10));            // 128 KiB
  float*          C      = (float*)(wsb + base + (512l << 10));            // 32 B
  int*            counts = (int*)  (wsb + base + (512l << 10) + 1024);     // 128 B

  k_gate<<<2048 + 2048, 256, 0, stream>>>(x, gw, t0, xbf, eo, counts, ex, WT);
  k_topk<<<BB * EE, 1024, 0, stream>>>(t0, R, C, eo);
  k_post<<<128, 256, 0, stream>>>(eo, t0, R, C, counts, lists, gvals);
  k_gemm<<<1024 + (BB * NN) / 4, 256, 0, stream>>>(xbf, WT, counts, lists, gvals, eo, out);
}

// Round 22
// 101.259 us; speedup vs baseline: 1.0921x; 1.0357x over previous
//
#include <hip/hip_runtime.h>
#include <hip/hip_bf16.h>

#define BB 4
#define NN 8192
#define DD 512
#define EE 8
#define OUTD 512
#define TOPM 1024
#define EPSV 1e-6f
#define ITERS 8

using s16x8 = __attribute__((ext_vector_type(8))) short;
using f32x4 = __attribute__((ext_vector_type(4))) float;
typedef unsigned long long u64;

__device__ __forceinline__ unsigned short f2bf(float f) {
  unsigned u = __float_as_uint(f);
  return (unsigned short)((u + 0x7FFFu + ((u >> 16) & 1u)) >> 16);
}

__device__ __forceinline__ void gll16(const void* g, void* l) {
  __builtin_amdgcn_global_load_lds((const __attribute__((address_space(1))) void*)g,
                                   (__attribute__((address_space(3))) void*)l, 16, 0, 0);
}

// ---- gate logits -> t0 = log(max(x@gw, eps)); x -> bf16; expert transpose ----
// 4 rows/wave; gw held in 64 VGPRs (asm keep-alive), x loads batched up front.
__global__ __launch_bounds__(256) void k_gate(const float* __restrict__ x,
                                              const float* __restrict__ gw,
                                              float* __restrict__ t0,
                                              unsigned short* __restrict__ xbf,
                                              int* __restrict__ eo,
                                              int* __restrict__ counts,
                                              const float* __restrict__ W,
                                              unsigned short* __restrict__ WT) {
  const int tid = threadIdx.x;
  if (blockIdx.x >= 2048) {
    // ---- expert transpose: f32 [e][k][n] -> bf16 [e][n][k], 32x32 tiles ----
    __shared__ float tl[32][33];
    const int widx = blockIdx.x - 2048;          // 0..2047
    const int e = widx >> 8, rem = widx & 255;
    const int k0 = (rem >> 4) * 32, n0 = (rem & 15) * 32;
    const int ty = tid >> 5, tx = tid & 31;
    const float* src = W + ((long)e * DD + k0) * OUTD + n0;
#pragma unroll
    for (int j = 0; j < 4; ++j)
      tl[ty + j * 8][tx] = src[(long)(ty + j * 8) * OUTD + tx];
    __syncthreads();
    unsigned short* dst = WT + ((long)e * OUTD + n0) * DD + k0;
#pragma unroll
    for (int j = 0; j < 4; ++j)
      dst[(long)(ty + j * 8) * DD + tx] = f2bf(tl[tx][ty + j * 8]);
    return;
  }
  if (tid < 16) eo[blockIdx.x * 16 + tid] = -1;                   // 2048*16 = 32768
  if (blockIdx.x == 0 && tid >= 64 && tid < 64 + BB * EE) counts[tid - 64] = 0;
  const int lane = tid & 63;
  const int w    = tid >> 6;
  // gw[k][e], k = lane*8 .. lane*8+7 -> 64 floats, forced register-resident
  float gwf[64];
  const float* gb = gw + (lane * 8) * EE;
#pragma unroll
  for (int q = 0; q < 16; ++q) {
    float4 t = *(const float4*)(gb + q * 4);
    gwf[q * 4 + 0] = t.x; gwf[q * 4 + 1] = t.y;
    gwf[q * 4 + 2] = t.z; gwf[q * 4 + 3] = t.w;
  }
#pragma unroll
  for (int q = 0; q < 64; ++q) asm volatile("" : "+v"(gwf[q]));   // defeat remat

  const long row0 = (long)blockIdx.x * 16 + w * 4;
  float4 xa[4], xb[4];
#pragma unroll
  for (int i = 0; i < 4; ++i) {
    const float* xr = x + (row0 + i) * DD + lane * 8;
    xa[i] = *(const float4*)(xr);
    xb[i] = *(const float4*)(xr + 4);
  }
  float vout[4];
#pragma unroll
  for (int i = 0; i < 4; ++i) {
    float xv[8] = {xa[i].x, xa[i].y, xa[i].z, xa[i].w,
                   xb[i].x, xb[i].y, xb[i].z, xb[i].w};
    s16x8 xo;
#pragma unroll
    for (int j = 0; j < 8; ++j) xo[j] = (short)f2bf(xv[j]);
    *(s16x8*)(xbf + (row0 + i) * DD + lane * 8) = xo;

    float acc[8] = {0.f,0.f,0.f,0.f,0.f,0.f,0.f,0.f};
#pragma unroll
    for (int q = 0; q < 8; ++q)
#pragma unroll
      for (int e = 0; e < 8; ++e) acc[e] += xv[q] * gwf[q * 8 + e];
    // select+shuffle halving fold: 8 arrays -> e=lane&7 in 7 shuffles, +3 wide
    const bool o1 = lane & 1;
    float own, oth, b0, b1, b2, b3, c0, c1, v;
    own = o1 ? acc[1] : acc[0]; oth = o1 ? acc[0] : acc[1];
    b0 = own + __shfl_xor(oth, 1);
    own = o1 ? acc[3] : acc[2]; oth = o1 ? acc[2] : acc[3];
    b1 = own + __shfl_xor(oth, 1);
    own = o1 ? acc[5] : acc[4]; oth = o1 ? acc[4] : acc[5];
    b2 = own + __shfl_xor(oth, 1);
    own = o1 ? acc[7] : acc[6]; oth = o1 ? acc[6] : acc[7];
    b3 = own + __shfl_xor(oth, 1);
    const bool o2 = lane & 2;
    own = o2 ? b1 : b0; oth = o2 ? b0 : b1;
    c0 = own + __shfl_xor(oth, 2);
    own = o2 ? b3 : b2; oth = o2 ? b2 : b3;
    c1 = own + __shfl_xor(oth, 2);
    const bool o4 = lane & 4;
    own = o4 ? c1 : c0; oth = o4 ? c0 : c1;
    v = own + __shfl_xor(oth, 4);
    v += __shfl_xor(v, 8);
    v += __shfl_xor(v, 16);
    v += __shfl_xor(v, 32);
    vout[i] = v;              // e = lane&7, all lanes
  }
  // coalesced t0 store: lanes 0..31 cover 4 rows x 8 experts
  const int gsel = lane >> 3;
  float vsel = vout[0];
  vsel = (gsel == 1) ? vout[1] : vsel;
  vsel = (gsel == 2) ? vout[2] : vsel;
  vsel = (gsel == 3) ? vout[3] : vsel;
  if (lane < 32) t0[row0 * EE + lane] = logf(fmaxf(vsel, EPSV));
}

// ---- fused: linear-domain Sinkhorn (redundant per e-block, bit-identical) +
// ---- exact top-1024 radix select, 3 passes of 12/12/8 bits (4096-bin hist:
// ---- spreads LDS atomics of concentrated log-gate keys ~16x vs 8-bit pass-1,
// ---- and saves one full 8192-key sweep).
__global__ __attribute__((amdgpu_waves_per_eu(4, 4)))
__launch_bounds__(1024) void k_topk(const float* __restrict__ t0,
                                    float* __restrict__ R,
                                    float* __restrict__ C,
                                    int* __restrict__ expert_of) {
  __shared__ unsigned key[NN];            // 32 KiB (holds tvm bits during Sinkhorn)
  __shared__ int hist[4096];              // 16 KiB
  __shared__ int bcast[2];
  __shared__ int wsum[16];
  __shared__ float ws[16][8], Csh[8], Ssh[8];
  const int b = blockIdx.x >> 3, e = blockIdx.x & 7;
  const int tid = threadIdx.x;
  const int wv = tid >> 6, ln = tid & 63;
  const float* tb = t0 + (long)b * NN * EE;

  // ---- Sinkhorn: thread owns rows {j*1024+tid}; E = exp(t0); u = 1/D; v = 1/S ----
  float E[8][8], u[8], dl[8];
#pragma unroll
  for (int j = 0; j < 8; ++j) {
    const float* p = tb + (long)(j * 1024 + tid) * EE;
    float4 a = *(const float4*)p, b4 = *(const float4*)(p + 4);
    E[j][0] = expf(a.x);  E[j][1] = expf(a.y);
    E[j][2] = expf(a.z);  E[j][3] = expf(a.w);
    E[j][4] = expf(b4.x); E[j][5] = expf(b4.y);
    E[j][6] = expf(b4.z); E[j][7] = expf(b4.w);
    key[j * 1024 + tid] = __float_as_uint(p[e]);   // park own-expert t0 in LDS
    u[j] = 1.f;
  }
#pragma unroll
  for (int j = 0; j < 8; ++j)
#pragma unroll
    for (int e2 = 0; e2 < 8; ++e2)
      asm volatile("" : "+v"(E[j][e2]));           // keep-alive (best effort)
  for (int it = 0; it < ITERS; ++it) {
    float P[8] = {0.f,0.f,0.f,0.f,0.f,0.f,0.f,0.f};
#pragma unroll
    for (int j = 0; j < 8; ++j)
#pragma unroll
      for (int e2 = 0; e2 < 8; ++e2) P[e2] += E[j][e2] * u[j];
#pragma unroll
    for (int d = 1; d <= 4; d <<= 1) {
#pragma unroll
      for (int e2 = 0; e2 < 8; ++e2) {
        float tmp = __shfl_xor(P[e2], d);
        P[e2] += ((ln & d) == (e2 & d)) ? tmp : 0.f;
      }
    }
    float pv = P[0];
#pragma unroll
    for (int e2 = 1; e2 < 8; ++e2) pv = ((ln & 7) == e2) ? P[e2] : pv;
#pragma unroll
    for (int d = 8; d < 64; d <<= 1) pv += __shfl_xor(pv, d);
    if (ln < 8) ws[wv][ln] = pv;
    __syncthreads();
    if (tid < 64) {
      const int q = ln >> 3, e2 = ln & 7;
      float s = ws[q][e2] + ws[q + 8][e2];
#pragma unroll
      for (int d = 8; d < 64; d <<= 1) s += __shfl_xor(s, d);
      if (ln < 8) { Csh[ln] = 1.f / s; Ssh[ln] = s; }
    }
    __syncthreads();
    float vv[8];
#pragma unroll
    for (int e2 = 0; e2 < 8; ++e2) vv[e2] = Csh[e2];
#pragma unroll
    for (int j = 0; j < 8; ++j) {
      float d0 = E[j][0] * vv[0];
#pragma unroll
      for (int e2 = 1; e2 < 8; ++e2) d0 += E[j][e2] * vv[e2];
      dl[j] = d0;
      u[j] = 1.f / d0;
    }
    __syncthreads();   // protect ws/Csh WAR before next iteration's writes
  }
  if (e == 0) {        // one block per batch persists R/C for k_post
#pragma unroll
    for (int j = 0; j < 8; ++j) R[(long)b * NN + j * 1024 + tid] = logf(dl[j]);
    if (tid < 8) C[b * EE + tid] = logf(Ssh[tid]);
  }

  // ---- keys + pass-A 12-bit histogram (tvm from LDS, R register-local) ----
  {
    int4 z4 = make_int4(0, 0, 0, 0);
    *(int4*)&hist[tid * 4] = z4;
  }
  __syncthreads();
#pragma unroll
  for (int j = 0; j < 8; ++j) {
    const int n = j * 1024 + tid;
    float f = __uint_as_float(key[n]) - logf(dl[j]);
    unsigned uk = __float_as_uint(f);
    uk = (uk & 0x80000000u) ? ~uk : (uk | 0x80000000u);   // sortable
    key[n] = uk;
    atomicAdd(&hist[uk >> 20], 1);
  }
  __syncthreads();

  unsigned prefix = 0;
  int k = TOPM;
  for (int pass = 0; pass < 3; ++pass) {
    // ---- suffix-scan of 4096 bins: all 1024 threads, 4 bins each ----
    const int4 h4 = *(const int4*)&hist[tid * 4];
    const int s3 = h4.w, s2 = h4.z + s3, s1 = h4.y + s2, s0 = h4.x + s1;
    int inc = s0;
#pragma unroll
    for (int d = 1; d < 64; d <<= 1) {
      int o = __shfl_down(inc, d);
      if (ln + d < 64) inc += o;
    }
    if (ln == 0) wsum[wv] = inc;        // wave total
    __syncthreads();
    if (tid == 0) {
      int run = 0;
      for (int w2 = 15; w2 >= 0; --w2) { int t2 = wsum[w2]; wsum[w2] = run; run += t2; }
    }
    __syncthreads();
    const int above = wsum[wv] + (inc - s0);  // keys in bins above this thread's 4
    const int c0 = above + s0, c1 = above + s1, c2 = above + s2, c3 = above + s3;
    if (c0 >= k && c1 < k)    { bcast[0] = k - c1;    bcast[1] = tid * 4 + 0; }
    if (c1 >= k && c2 < k)    { bcast[0] = k - c2;    bcast[1] = tid * 4 + 1; }
    if (c2 >= k && c3 < k)    { bcast[0] = k - c3;    bcast[1] = tid * 4 + 2; }
    if (c3 >= k && above < k) { bcast[0] = k - above; bcast[1] = tid * 4 + 3; }
    __syncthreads();
    k = bcast[0];
    const unsigned bin = (unsigned)bcast[1];
    if (pass == 0)      prefix = bin << 20;
    else if (pass == 1) prefix |= bin << 8;
    else                prefix |= bin;
    if (pass == 2) break;
    // ---- rebuild hist for next digit among prefix-matching keys ----
    {
      int4 z4 = make_int4(0, 0, 0, 0);
      *(int4*)&hist[tid * 4] = z4;
    }
    __syncthreads();
    if (pass == 0) {
      const unsigned pa = prefix >> 20;
      for (int n = tid; n < NN; n += 1024) {
        unsigned uk = key[n];
        if ((uk >> 20) == pa) atomicAdd(&hist[(uk >> 8) & 4095], 1);
      }
    } else {
      const unsigned pb = prefix >> 8;
      for (int n = tid; n < NN; n += 1024) {
        unsigned uk = key[n];
        if ((uk >> 8) == pb) atomicAdd(&hist[uk & 255], 1);
      }
    }
    __syncthreads();
  }
  const unsigned theta = prefix;
  const int need = k;                  // ties (==theta) to take, lowest index first
  const int base = tid * 8;            // contiguous chunks -> deterministic index order
  int c = 0;
#pragma unroll
  for (int j = 0; j < 8; ++j) if (key[base + j] == theta) ++c;
  int inc2 = c;
#pragma unroll
  for (int d = 1; d < 64; d <<= 1) {
    int o = __shfl_up(inc2, d);
    if (ln >= d) inc2 += o;
  }
  if (ln == 63) wsum[wv] = inc2;
  __syncthreads();
  if (tid == 0) {
    int runv = 0;
    for (int i = 0; i < 16; ++i) { int t2 = wsum[i]; wsum[i] = runv; runv += t2; }
  }
  __syncthreads();
  int run = wsum[wv] + inc2 - c;       // exclusive prefix of this thread's ties
  int* eo = expert_of + b * NN;
  for (int j = 0; j < 8; ++j) {
    int n = base + j;
    unsigned uk = key[n];
    bool sel = false;
    if (uk > theta) sel = true;
    else if (uk == theta) { if (run < need) sel = true; ++run; }
    if (sel) atomicMax(&eo[n], e);     // np scatter: largest expert index wins
  }
}

// ---- compact per-(b,e) token lists + gate values (list-build only; 128 blocks) ----
__global__ __launch_bounds__(256) void k_post(const int* __restrict__ expert_of,
                                              const float* __restrict__ t0,
                                              const float* __restrict__ R,
                                              const float* __restrict__ C,
                                              int* __restrict__ counts,
                                              int* __restrict__ lists,
                                              float* __restrict__ gvals) {
  __shared__ int hist8[8], base8[8];
  const int tid = threadIdx.x;
  if (tid < 8) hist8[tid] = 0;
  __syncthreads();
  const long i = (long)blockIdx.x * 256 + tid;     // block within one batch
  const int b = (int)(i >> 13);
  const int e = expert_of[i];
  int lpos = -1;
  if (e >= 0) lpos = atomicAdd(&hist8[e], 1);      // LDS atomic: ns-scale
  __syncthreads();
  if (tid < 8 && hist8[tid] > 0)
    base8[tid] = atomicAdd(&counts[b * EE + tid], hist8[tid]);  // 1 RMW per (block,e)
  __syncthreads();
  if (e >= 0) {
    const int n = (int)(i & (NN - 1));
    const int be = b * EE + e;
    const int slot = be * TOPM + base8[e] + lpos;
    lists[slot] = n;
    gvals[slot] = expf(t0[i * EE + e] - C[be] - R[i]);
  }
}

// ---- gathered bf16 MFMA GEMM v2 (blocks 0..1023) + zero unselected rows (1024+) ----
__global__ __launch_bounds__(256) void k_gemm(const unsigned short* __restrict__ xbf,
                                              const unsigned short* __restrict__ WT,
                                              const int* __restrict__ counts,
                                              const int* __restrict__ lists,
                                              const float* __restrict__ gvals,
                                              const int* __restrict__ eo,
                                              float* __restrict__ out) {
  const int tid = threadIdx.x;
  if (blockIdx.x >= 1024) {
    // zero output rows of unselected tokens (backfills CUs behind gemm tiles)
    const int row = (blockIdx.x - 1024) * 4 + (tid >> 6);
    if (eo[row] >= 0) return;
    const int ln = tid & 63;
    float4 z = make_float4(0.f, 0.f, 0.f, 0.f);
    float4* p = (float4*)(out + (long)row * OUTD) + ln;
    p[0] = z; p[64] = z;
    return;
  }
  const int id = blockIdx.x;                 // 1024 = xq*256 + be*8 + yq
  const int xq = id >> 8;                    // 0..3  col tile (A-sharing -> same XCD)
  const int be = (id >> 3) & 31;             // b*8+e
  const int yq = id & 7;                     // 0..7  row tile
  const int b = be >> 3, e = be & 7;
  const int cnt = counts[be];
  const int r0 = yq * 128;
  if (r0 >= cnt) return;
  const int c0 = xq * 128;

  __shared__ unsigned short As[128 * 64];    // 16 KiB
  __shared__ unsigned short Bs[128 * 64];    // 16 KiB
  __shared__ int   rowTok[128];
  __shared__ float rowG[128];

  if (tid < 128) {
    int r = r0 + tid;
    rowTok[tid] = (r < cnt) ? lists[be * TOPM + r] : -1;
    rowG[tid]   = (r < cnt) ? gvals[be * TOPM + r] : 0.f;
  }
  __syncthreads();

  const int w = tid >> 6, l = tid & 63;
  const int rbase = w * 32 + (l >> 3);
  const int sL = l & 7;
  const unsigned short* xb_b = xbf + (long)b * NN * DD;
  const unsigned short* wt_e = WT + (long)e * OUTD * DD;
  int tokc[4]; int sGa[4];
#pragma unroll
  for (int c = 0; c < 4; ++c) {
    int r = rbase + c * 8;
    int tk = rowTok[r]; if (tk < 0) tk = 0;
    tokc[c] = tk;
    sGa[c] = (sL ^ (r & 7)) * 8;             // pre-swizzled global k-slot (elems)
  }

  const int wr = w >> 1, wc = w & 1;
  const int fr = l & 15, fq = l >> 4;
  int aoff[4][2], boff[4][2];
#pragma unroll
  for (int m = 0; m < 4; ++m) {
#pragma unroll
    for (int kk = 0; kk < 2; ++kk) {
      int row = wr * 64 + m * 16 + fr;
      aoff[m][kk] = row * 64 + (((fq + 4 * kk) ^ (row & 7)) * 8);
      int col = wc * 64 + m * 16 + fr;
      boff[m][kk] = col * 64 + (((fq + 4 * kk) ^ (col & 7)) * 8);
    }
  }

  f32x4 acc[4][4] = {};

#define STAGE(kb) {                                                          \
    int ko = (kb) * 64;                                                      \
    _Pragma("unroll")                                                        \
    for (int c = 0; c < 4; ++c) {                                            \
      int r = rbase + c * 8;                                                 \
      gll16(xb_b + (long)tokc[c] * DD + ko + sGa[c],                         \
            As + (w * 32 + c * 8) * 64);                                     \
      gll16(wt_e + (long)(c0 + r) * DD + ko + sGa[c],                        \
            Bs + (w * 32 + c * 8) * 64);                                     \
    }                                                                        \
  }

  STAGE(0);
  for (int kb = 0; kb < 8; ++kb) {
    __syncthreads();
    s16x8 af[4][2], bf_[4][2];
#pragma unroll
    for (int m = 0; m < 4; ++m) {
      af[m][0] = *(const s16x8*)(As + aoff[m][0]);
      af[m][1] = *(const s16x8*)(As + aoff[m][1]);
      bf_[m][0] = *(const s16x8*)(Bs + boff[m][0]);
      bf_[m][1] = *(const s16x8*)(Bs + boff[m][1]);
    }
    __syncthreads();
    if (kb < 7) STAGE(kb + 1);
#pragma unroll
    for (int kk = 0; kk < 2; ++kk)
#pragma unroll
      for (int m = 0; m < 4; ++m)
#pragma unroll
        for (int n = 0; n < 4; ++n)
          acc[m][n] = __builtin_amdgcn_mfma_f32_16x16x32_bf16(af[m][kk], bf_[n][kk], acc[m][n], 0, 0, 0);
  }
#undef STAGE

  // epilogue: C/D layout col=lane&15, row=(lane>>4)*4+reg
#pragma unroll
  for (int m = 0; m < 4; ++m) {
    int rbase2 = wr * 64 + m * 16 + fq * 4;
    int tok[4]; float g[4];
#pragma unroll
    for (int j = 0; j < 4; ++j) { tok[j] = rowTok[rbase2 + j]; g[j] = rowG[rbase2 + j]; }
#pragma unroll
    for (int n = 0; n < 4; ++n) {
      int col = c0 + wc * 64 + n * 16 + fr;
#pragma unroll
      for (int j = 0; j < 4; ++j) {
        if (tok[j] >= 0)
          out[((long)b * NN + tok[j]) * OUTD + col] = acc[m][n][j] * g[j];
      }
    }
  }
}

extern "C" void kernel_launch(void* const* d_in, const int* in_sizes, int n_in,
                              void* d_out, int out_size, void* d_ws, size_t ws_size,
                              hipStream_t stream) {
  const float* x  = (const float*)d_in[0];
  const float* gw = (const float*)d_in[1];
  const float* ex = (const float*)d_in[2];
  float* out = (float*)d_out;

  char* wsb = (char*)d_ws;
  float*          t0     = (float*)(wsb);                          // 1 MiB
  unsigned short* xbf    = (unsigned short*)(wsb + (1l << 20));    // 32 MiB
  unsigned short* WT     = (unsigned short*)(wsb + (33l << 20));   // 4 MiB
  const long base = 37l << 20;
  float*          R      = (float*)(wsb + base);                           // 128 KiB
  int*            eo     = (int*)  (wsb + base + (128l << 10));            // 128 KiB
  int*            lists  = (int*)  (wsb + base + (256l << 10));            // 128 KiB
  float*          gvals  = (float*)(wsb + base + (384l << 10));            // 128 KiB
  float*          C      = (float*)(wsb + base + (512l << 10));            // 32 B
  int*            counts = (int*)  (wsb + base + (512l << 10) + 1024);     // 128 B

  k_gate<<<2048 + 2048, 256, 0, stream>>>(x, gw, t0, xbf, eo, counts, ex, WT);
  k_topk<<<BB * EE, 1024, 0, stream>>>(t0, R, C, eo);
  k_post<<<128, 256, 0, stream>>>(eo, t0, R, C, counts, lists, gvals);
  k_gemm<<<1024 + (BB * NN) / 4, 256, 0, stream>>>(xbf, WT, counts, lists, gvals, eo, out);
}